// Round 1
// baseline (287.897 us; speedup 1.0000x reference)
//
#include <hip/hip_runtime.h>
#include <hip/hip_bf16.h>

#define S_LEN 2048
#define DH    64
#define NBH   32          // B*H
#define QTILE 64
#define KVT   64

typedef __attribute__((ext_vector_type(8))) short short8;
typedef __attribute__((ext_vector_type(4))) float f32x4;

static __device__ __forceinline__ unsigned short f2bf(float f) {
    __hip_bfloat16 h = __float2bfloat16(f);
    return *reinterpret_cast<unsigned short*>(&h);
}
static __device__ __forceinline__ unsigned pack2(float a, float b) {
    return (unsigned)f2bf(a) | ((unsigned)f2bf(b) << 16);
}

// ---------------------------------------------------------------------------
// Main flash-attention kernel.
// grid = (S/QTILE, B*H), block = 256 (4 waves, 16 q-rows per wave)
// LDS tiles use XOR chunk swizzle: 16B-chunk index ^= (row & 7)  (rows are 128B)
// ---------------------------------------------------------------------------
__global__ __launch_bounds__(256)
void attn_fwd(const float* __restrict__ Q, const float* __restrict__ K,
              const float* __restrict__ V, const int* __restrict__ pad,
              float* __restrict__ out)
{
    __shared__ __align__(16) char ldsK[KVT * 128];     // [key][d]  bf16, swizzled
    __shared__ __align__(16) char ldsV[DH * 128];      // [d][key]  bf16 (transposed), swizzled
    __shared__ __align__(16) char ldsP[4][16 * 128];   // per-wave P bounce, swizzled
    __shared__ int ldsPad[KVT];

    const int tid  = threadIdx.x;
    const int lane = tid & 63;
    const int wid  = tid >> 6;
    const int bx   = blockIdx.x;            // q tile index
    const int bh   = blockIdx.y;            // b*16 + h
    const int b    = bh >> 4;

    const int q0   = bx * QTILE;
    const int q0w  = q0 + wid * 16;
    const long base = (long)bh * S_LEN * DH;

    const int lr = lane & 15;               // A-row / C-col
    const int lg = lane >> 4;               // group 0..3

    // ---- Q fragments (A operand), scale = (1/8)*log2(e) folded in ----
    const float QS = 0.18033688011112042f;
    short8 aq[2];
    {
        const float* qp = Q + base + (long)(q0w + lr) * DH;
        #pragma unroll
        for (int s = 0; s < 2; ++s) {
            int d0 = s * 32 + lg * 8;
            float4 x = *reinterpret_cast<const float4*>(qp + d0);
            float4 y = *reinterpret_cast<const float4*>(qp + d0 + 4);
            union { short8 s8; unsigned u[4]; } u;
            u.u[0] = pack2(x.x * QS, x.y * QS);
            u.u[1] = pack2(x.z * QS, x.w * QS);
            u.u[2] = pack2(y.x * QS, y.y * QS);
            u.u[3] = pack2(y.z * QS, y.w * QS);
            aq[s] = u.s8;
        }
    }

    f32x4 o[4];
    float m_run[4], l_run[4];
    #pragma unroll
    for (int r = 0; r < 4; ++r) {
        o[r] = (f32x4){0.f, 0.f, 0.f, 0.f};
        m_run[r] = -1e30f;
        l_run[r] = 0.f;
    }

    const int nkv = bx + 1;                 // causal: keys up to q0+63
    for (int kv = 0; kv < nkv; ++kv) {
        const int kv0 = kv * KVT;
        __syncthreads();                    // protect LDS from previous iteration readers

        // ---- stage K tile: fp32 -> bf16, [key][d], swizzled ----
        {
            const float* kp = K + base + (long)kv0 * DH;
            #pragma unroll
            for (int it = 0; it < 4; ++it) {
                int f   = it * 1024 + tid * 4;
                int row = f >> 6;
                int dc  = f & 63;
                float4 x = *reinterpret_cast<const float4*>(kp + f);
                unsigned lo = pack2(x.x, x.y);
                unsigned hi = pack2(x.z, x.w);
                int chunk = (dc >> 3) ^ (row & 7);
                *reinterpret_cast<uint2*>(ldsK + row * 128 + chunk * 16 + (dc & 7) * 2)
                    = make_uint2(lo, hi);
            }
        }
        // ---- stage V tile transposed: [d][key] bf16, swizzled ----
        {
            const float* vp = V + base + (long)kv0 * DH;
            int dg = tid & 15;              // d = dg*4 .. +3
            int kq = tid >> 4;              // k = kq*4 .. +3
            float rv[4][4];
            #pragma unroll
            for (int j = 0; j < 4; ++j) {
                float4 t = *reinterpret_cast<const float4*>(vp + (kq * 4 + j) * DH + dg * 4);
                rv[j][0] = t.x; rv[j][1] = t.y; rv[j][2] = t.z; rv[j][3] = t.w;
            }
            #pragma unroll
            for (int i = 0; i < 4; ++i) {
                int d = dg * 4 + i;
                unsigned lo = pack2(rv[0][i], rv[1][i]);
                unsigned hi = pack2(rv[2][i], rv[3][i]);
                int chunk = (kq >> 1) ^ (d & 7);
                *reinterpret_cast<uint2*>(ldsV + d * 128 + chunk * 16 + (kq & 1) * 8)
                    = make_uint2(lo, hi);
            }
        }
        if (tid < KVT) ldsPad[tid] = pad[b * S_LEN + kv0 + tid];
        __syncthreads();

        // ---- S = Q K^T (base-2 domain): 4 key-tiles x 2 d-slices ----
        f32x4 sfr[4];
        #pragma unroll
        for (int kt = 0; kt < 4; ++kt) {
            int krow = kt * 16 + lr;
            f32x4 acc = (f32x4){0.f, 0.f, 0.f, 0.f};
            #pragma unroll
            for (int s = 0; s < 2; ++s) {
                int chunk = (s * 4 + lg) ^ (krow & 7);
                const short8 bk = *reinterpret_cast<const short8*>(ldsK + krow * 128 + chunk * 16);
                acc = __builtin_amdgcn_mfma_f32_16x16x32_bf16(aq[s], bk, acc, 0, 0, 0);
            }
            sfr[kt] = acc;
        }

        // ---- mask + online softmax (per r: row = lg*4 + r) ----
        int  kcol[4]; bool padm[4];
        #pragma unroll
        for (int kt = 0; kt < 4; ++kt) {
            kcol[kt] = kv0 + kt * 16 + lr;
            padm[kt] = (ldsPad[kt * 16 + lr] != 0);
        }
        #pragma unroll
        for (int r = 0; r < 4; ++r) {
            int qg = q0w + lg * 4 + r;
            float sv[4];
            #pragma unroll
            for (int kt = 0; kt < 4; ++kt) {
                float v = sfr[kt][r];
                sv[kt] = (padm[kt] || kcol[kt] > qg) ? -1e30f : v;
            }
            float bm = fmaxf(fmaxf(sv[0], sv[1]), fmaxf(sv[2], sv[3]));
            #pragma unroll
            for (int off = 1; off < 16; off <<= 1) bm = fmaxf(bm, __shfl_xor(bm, off));
            float mnew = fmaxf(m_run[r], bm);
            float c = exp2f(m_run[r] - mnew);
            m_run[r] = mnew;
            float rs = 0.f;
            int row = lg * 4 + r;
            #pragma unroll
            for (int kt = 0; kt < 4; ++kt) {
                float p = exp2f(sv[kt] - mnew);
                rs += p;
                int col = kt * 16 + lr;
                int chunk = (col >> 3) ^ (row & 7);
                *reinterpret_cast<unsigned short*>(ldsP[wid] + row * 128 + chunk * 16 + (col & 7) * 2)
                    = f2bf(p);
            }
            #pragma unroll
            for (int off = 1; off < 16; off <<= 1) rs += __shfl_xor(rs, off);
            l_run[r] = l_run[r] * c + rs;
            #pragma unroll
            for (int dt = 0; dt < 4; ++dt) o[dt][r] *= c;
        }

        // wave-internal: make P writes visible to our own ds_reads
        asm volatile("s_waitcnt lgkmcnt(0)" ::: "memory");
        __builtin_amdgcn_sched_barrier(0);

        // ---- PV: O += P * V ----
        short8 pa[2];
        #pragma unroll
        for (int ks = 0; ks < 2; ++ks) {
            int chunk = (ks * 4 + lg) ^ (lr & 7);
            pa[ks] = *reinterpret_cast<const short8*>(ldsP[wid] + lr * 128 + chunk * 16);
        }
        #pragma unroll
        for (int dt = 0; dt < 4; ++dt) {
            int drow = dt * 16 + lr;
            #pragma unroll
            for (int ks = 0; ks < 2; ++ks) {
                int chunk = (ks * 4 + lg) ^ (drow & 7);
                const short8 bv = *reinterpret_cast<const short8*>(ldsV + drow * 128 + chunk * 16);
                o[dt] = __builtin_amdgcn_mfma_f32_16x16x32_bf16(pa[ks], bv, o[dt], 0, 0, 0);
            }
        }
    }

    // ---- epilogue ----
    float inv[4];
    #pragma unroll
    for (int r = 0; r < 4; ++r) inv[r] = 1.0f / l_run[r];
    float* op = out + base + (long)q0w * DH;
    #pragma unroll
    for (int r = 0; r < 4; ++r) {
        int q = lg * 4 + r;
        #pragma unroll
        for (int dt = 0; dt < 4; ++dt)
            op[(long)q * DH + dt * 16 + lr] = o[dt][r] * inv[r];
    }
}

// ---------------------------------------------------------------------------
// first_zero[b] = min k with pad[b,k]==0 (S if none)
// ---------------------------------------------------------------------------
__global__ void fz_kernel(const int* __restrict__ pad, int* __restrict__ fz)
{
    int b = blockIdx.x;
    __shared__ int red[256];
    int local = S_LEN;
    for (int k = threadIdx.x; k < S_LEN; k += 256)
        if (pad[b * S_LEN + k] == 0 && k < local) local = k;
    red[threadIdx.x] = local;
    __syncthreads();
    for (int s = 128; s > 0; s >>= 1) {
        if (threadIdx.x < s) red[threadIdx.x] = min(red[threadIdx.x], red[threadIdx.x + s]);
        __syncthreads();
    }
    if (threadIdx.x == 0) fz[b] = red[0];
}

// ---------------------------------------------------------------------------
// Rows q < first_zero[b] have ALL keys masked -> reference softmax degenerates
// to uniform 1/2048 over ALL keys -> out = mean(V). Overwrite those rows.
// grid = B*H blocks.
// ---------------------------------------------------------------------------
__global__ void fixup_kernel(const float* __restrict__ V, const int* __restrict__ fz,
                             float* __restrict__ out)
{
    int bh = blockIdx.x;
    int b  = bh >> 4;
    int n  = fz[b];
    if (n <= 0) return;

    int d    = threadIdx.x & 63;
    int part = threadIdx.x >> 6;
    const float* vp = V + (long)bh * S_LEN * DH;
    float s = 0.f;
    for (int k = part; k < S_LEN; k += 4) s += vp[(long)k * DH + d];

    __shared__ float red[4][64];
    __shared__ float mean[64];
    red[part][d] = s;
    __syncthreads();
    if (part == 0)
        mean[d] = (red[0][d] + red[1][d] + red[2][d] + red[3][d]) * (1.0f / 2048.0f);
    __syncthreads();

    float* op = out + (long)bh * S_LEN * DH;
    for (int i = threadIdx.x; i < n * 64; i += 256) op[i] = mean[i & 63];
}

extern "C" void kernel_launch(void* const* d_in, const int* in_sizes, int n_in,
                              void* d_out, int out_size, void* d_ws, size_t ws_size,
                              hipStream_t stream)
{
    const float* Q   = (const float*)d_in[0];
    const float* K   = (const float*)d_in[1];
    const float* V   = (const float*)d_in[2];
    const int*   pad = (const int*)d_in[3];
    float* out = (float*)d_out;
    int*   fz  = (int*)d_ws;

    fz_kernel<<<dim3(2), dim3(256), 0, stream>>>(pad, fz);
    attn_fwd<<<dim3(S_LEN / QTILE, NBH), dim3(256), 0, stream>>>(Q, K, V, pad, out);
    fixup_kernel<<<dim3(NBH), dim3(256), 0, stream>>>(V, fz, out);
}

// Round 2
// 225.702 us; speedup vs baseline: 1.2756x; 1.2756x over previous
//
#include <hip/hip_runtime.h>
#include <hip/hip_bf16.h>

#define S_LEN 2048
#define DH    64
#define NBH   32          // B*H
#define QT    128         // q rows per block (4 warps x 32)
#define KVT   64

typedef __attribute__((ext_vector_type(8)))  short short8;
typedef __attribute__((ext_vector_type(4)))  float f32x4;
typedef __attribute__((ext_vector_type(16))) float f32x16;

static __device__ __forceinline__ unsigned cvtpk_bf16(float a, float b) {
    unsigned r;
    asm("v_cvt_pk_bf16_f32 %0, %1, %2" : "=v"(r) : "v"(a), "v"(b));
    return r;
}

// ---------------------------------------------------------------------------
// Flash attention, swapped-operand 32x32x16 MFMA structure.
// grid = (S/QT, B*H), block = 256 (4 waves, 32 q-rows per wave)
// K LDS:  [key][d]  bf16, rows 128B, chunk ^= row&7 swizzle
// V LDS:  [d][key]  bf16 (transposed), same swizzle
// ---------------------------------------------------------------------------
__global__ __launch_bounds__(256)
void attn_fwd(const float* __restrict__ Q, const float* __restrict__ K,
              const float* __restrict__ V, const int* __restrict__ pad,
              float* __restrict__ out)
{
    __shared__ __align__(16) char  ldsK[2][KVT * 128];
    __shared__ __align__(16) char  ldsV[2][DH * 128];
    __shared__ __align__(16) float ldsPB[2][KVT];

    const int tid  = threadIdx.x;
    const int lane = tid & 63;
    const int wid  = tid >> 6;
    const int bx   = gridDim.x - 1 - blockIdx.x;   // heavy (diagonal-long) blocks first
    const int bh   = blockIdx.y;
    const int b    = bh >> 4;

    const int q0   = bx * QT;
    const int q0w  = q0 + wid * 32;
    const long base = (long)bh * S_LEN * DH;

    const int lq = lane & 31;      // this lane's q-row (col of C) / key row (A)
    const int hi = lane >> 5;

    // ---- Q fragments (B operand), scale = (1/8)*log2(e) folded ----
    const float QS = 0.18033688011112042f;
    short8 bq[4];
    {
        const float* qp = Q + base + (long)(q0w + lq) * DH;
        #pragma unroll
        for (int s = 0; s < 4; ++s) {
            int d0 = s * 16 + hi * 8;
            f32x4 x = *(const f32x4*)(qp + d0);
            f32x4 y = *(const f32x4*)(qp + d0 + 4);
            union { short8 s8; unsigned u[4]; } u;
            u.u[0] = cvtpk_bf16(x[0] * QS, x[1] * QS);
            u.u[1] = cvtpk_bf16(x[2] * QS, x[3] * QS);
            u.u[2] = cvtpk_bf16(y[0] * QS, y[1] * QS);
            u.u[3] = cvtpk_bf16(y[2] * QS, y[3] * QS);
            bq[s] = u.s8;
        }
    }

    f32x16 o0, o1;
    #pragma unroll
    for (int r = 0; r < 16; ++r) { o0[r] = 0.f; o1[r] = 0.f; }
    float m_run = -1e30f, l_run = 0.f;

    const int nkv = 2 * (bx + 1);

    // staging registers (issued early, written to LDS late -> T14)
    f32x4 kst[4], vst[4];
    int   pst = 0;
    const int vdg = tid & 15, vkq = tid >> 4;
    const float* Kb = K + base;
    const float* Vb = V + base;

    auto stage_load = [&](int t) {
        const float* kp = Kb + t * (KVT * DH);
        #pragma unroll
        for (int i = 0; i < 4; ++i)
            kst[i] = *(const f32x4*)(kp + i * 1024 + tid * 4);
        const float* vp = Vb + t * (KVT * DH);
        #pragma unroll
        for (int j = 0; j < 4; ++j)
            vst[j] = *(const f32x4*)(vp + (vkq * 4 + j) * DH + vdg * 4);
        pst = pad[b * S_LEN + t * KVT + (tid & 63)];
    };
    auto stage_write = [&](int buf) {
        char* kB = ldsK[buf];
        #pragma unroll
        for (int i = 0; i < 4; ++i) {
            int f = i * 1024 + tid * 4;
            int row = f >> 6, dc = f & 63;
            unsigned lo = cvtpk_bf16(kst[i][0], kst[i][1]);
            unsigned h2 = cvtpk_bf16(kst[i][2], kst[i][3]);
            int ch = (dc >> 3) ^ (row & 7);
            *(uint2*)(kB + row * 128 + ch * 16 + (dc & 7) * 2) = make_uint2(lo, h2);
        }
        char* vB = ldsV[buf];
        #pragma unroll
        for (int i = 0; i < 4; ++i) {
            int d = vdg * 4 + i;
            unsigned lo = cvtpk_bf16(vst[0][i], vst[1][i]);
            unsigned h2 = cvtpk_bf16(vst[2][i], vst[3][i]);
            int ch = (vkq >> 1) ^ (d & 7);
            *(uint2*)(vB + d * 128 + ch * 16 + (vkq & 1) * 8) = make_uint2(lo, h2);
        }
        if (tid < KVT) ldsPB[buf][tid] = pst ? -1e30f : 0.f;
    };

    // prologue: stage tile 0
    stage_load(0);
    stage_write(0);
    __syncthreads();

    for (int t = 0; t < nkv; ++t) {
        const int cur = t & 1;
        const int kv0 = t * KVT;
        if (t + 1 < nkv) stage_load(t + 1);   // issue HBM loads early

        if (kv0 <= q0w + 31) {                // tile has unmasked keys for this warp
            const char*  kB = ldsK[cur];
            const char*  vB = ldsV[cur];
            const float* pb = ldsPB[cur];
            const int    rsw = lq & 7;

            // ---- acc init = pad bias (broadcast f32x4 reads) ----
            f32x16 s0, s1;
            #pragma unroll
            for (int g = 0; g < 4; ++g) {
                f32x4 p0 = *(const f32x4*)(pb + g * 8 + hi * 4);
                f32x4 p1 = *(const f32x4*)(pb + 32 + g * 8 + hi * 4);
                #pragma unroll
                for (int i = 0; i < 4; ++i) { s0[g * 4 + i] = p0[i]; s1[g * 4 + i] = p1[i]; }
            }

            // ---- S^T = K Q^T : rows=keys, cols=q ----
            #pragma unroll
            for (int s = 0; s < 4; ++s) {
                int ch = (((s * 2 + hi) ^ rsw) * 16);
                short8 ak0 = *(const short8*)(kB + lq * 128 + ch);
                short8 ak1 = *(const short8*)(kB + (32 + lq) * 128 + ch);
                s0 = __builtin_amdgcn_mfma_f32_32x32x16_bf16(ak0, bq[s], s0, 0, 0, 0);
                s1 = __builtin_amdgcn_mfma_f32_32x32x16_bf16(ak1, bq[s], s1, 0, 0, 0);
            }

            // ---- causal mask (diagonal tiles only) ----
            if (kv0 + 63 > q0w) {
                int q = q0w + lq;
                #pragma unroll
                for (int r = 0; r < 16; ++r) {
                    int key0 = kv0 + (r & 3) + 8 * (r >> 2) + 4 * hi;
                    if (key0 > q)      s0[r] = -1e30f;
                    if (key0 + 32 > q) s1[r] = -1e30f;
                }
            }

            // ---- online softmax, fully lane-local (row = lq) ----
            float bm = -1e30f;
            #pragma unroll
            for (int r = 0; r < 16; ++r) bm = fmaxf(bm, fmaxf(s0[r], s1[r]));
            bm = fmaxf(bm, __shfl_xor(bm, 32));
            float mnew = fmaxf(m_run, bm);
            float c = exp2f(m_run - mnew);
            m_run = mnew;
            float rs = 0.f;
            #pragma unroll
            for (int r = 0; r < 16; ++r) {
                float p0 = exp2f(s0[r] - mnew);
                float p1 = exp2f(s1[r] - mnew);
                s0[r] = p0; s1[r] = p1;
                rs += p0 + p1;
            }
            rs += __shfl_xor(rs, 32);
            l_run = l_run * c + rs;
            #pragma unroll
            for (int r = 0; r < 16; ++r) { o0[r] *= c; o1[r] *= c; }

            // ---- refragment P -> bf16 B-operand (cvt_pk + permlane32_swap) ----
            short8 pfr[4];
            #pragma unroll
            for (int fs = 0; fs < 4; ++fs) {
                const f32x16& sp = (fs < 2) ? s0 : s1;
                const int rb = (fs & 1) * 8;
                unsigned a0 = cvtpk_bf16(sp[rb + 0], sp[rb + 1]);
                unsigned b0 = cvtpk_bf16(sp[rb + 4], sp[rb + 5]);
                asm("v_permlane32_swap_b32 %0, %1" : "+v"(a0), "+v"(b0));
                unsigned a1 = cvtpk_bf16(sp[rb + 2], sp[rb + 3]);
                unsigned b1 = cvtpk_bf16(sp[rb + 6], sp[rb + 7]);
                asm("v_permlane32_swap_b32 %0, %1" : "+v"(a1), "+v"(b1));
                union { short8 s8; unsigned u[4]; } u;
                u.u[0] = a0; u.u[1] = a1; u.u[2] = b0; u.u[3] = b1;
                pfr[fs] = u.s8;
            }

            // ---- O^T += V^T P^T : rows=d, cols=q ----
            #pragma unroll
            for (int fs = 0; fs < 4; ++fs) {
                int ch = (((fs * 2 + hi) ^ rsw) * 16);
                short8 av0 = *(const short8*)(vB + lq * 128 + ch);
                short8 av1 = *(const short8*)(vB + (32 + lq) * 128 + ch);
                o0 = __builtin_amdgcn_mfma_f32_32x32x16_bf16(av0, pfr[fs], o0, 0, 0, 0);
                o1 = __builtin_amdgcn_mfma_f32_32x32x16_bf16(av1, pfr[fs], o1, 0, 0, 0);
            }
        }

        if (t + 1 < nkv) stage_write((t + 1) & 1);   // vmcnt drain + LDS write, late
        __syncthreads();
    }

    // ---- epilogue: out[q][d], q = lane-local ----
    float invl = 1.0f / l_run;
    float* op = out + base + (long)(q0w + lq) * DH;
    #pragma unroll
    for (int g = 0; g < 4; ++g) {
        f32x4 w0, w1;
        #pragma unroll
        for (int i = 0; i < 4; ++i) {
            w0[i] = o0[g * 4 + i] * invl;
            w1[i] = o1[g * 4 + i] * invl;
        }
        *(f32x4*)(op + g * 8 + hi * 4)      = w0;
        *(f32x4*)(op + 32 + g * 8 + hi * 4) = w1;
    }
}

// ---------------------------------------------------------------------------
// first_zero[b] = min k with pad[b,k]==0 (S if none)
// ---------------------------------------------------------------------------
__global__ void fz_kernel(const int* __restrict__ pad, int* __restrict__ fz)
{
    int b = blockIdx.x;
    __shared__ int red[256];
    int local = S_LEN;
    for (int k = threadIdx.x; k < S_LEN; k += 256)
        if (pad[b * S_LEN + k] == 0 && k < local) local = k;
    red[threadIdx.x] = local;
    __syncthreads();
    for (int s = 128; s > 0; s >>= 1) {
        if (threadIdx.x < s) red[threadIdx.x] = min(red[threadIdx.x], red[threadIdx.x + s]);
        __syncthreads();
    }
    if (threadIdx.x == 0) fz[b] = red[0];
}

// ---------------------------------------------------------------------------
// Rows q < first_zero[b]: reference softmax degenerates to uniform over ALL
// keys (scores all exactly -1e9 in fp32) -> out = mean(V). Overwrite them.
// ---------------------------------------------------------------------------
__global__ void fixup_kernel(const float* __restrict__ V, const int* __restrict__ fz,
                             float* __restrict__ out)
{
    int bh = blockIdx.x;
    int b  = bh >> 4;
    int n  = fz[b];
    if (n <= 0) return;

    int d    = threadIdx.x & 63;
    int part = threadIdx.x >> 6;
    const float* vp = V + (long)bh * S_LEN * DH;
    float s = 0.f;
    for (int k = part; k < S_LEN; k += 4) s += vp[(long)k * DH + d];

    __shared__ float red[4][64];
    __shared__ float mean[64];
    red[part][d] = s;
    __syncthreads();
    if (part == 0)
        mean[d] = (red[0][d] + red[1][d] + red[2][d] + red[3][d]) * (1.0f / 2048.0f);
    __syncthreads();

    float* op = out + (long)bh * S_LEN * DH;
    for (int i = threadIdx.x; i < n * 64; i += 256) op[i] = mean[i & 63];
}

extern "C" void kernel_launch(void* const* d_in, const int* in_sizes, int n_in,
                              void* d_out, int out_size, void* d_ws, size_t ws_size,
                              hipStream_t stream)
{
    const float* Q   = (const float*)d_in[0];
    const float* K   = (const float*)d_in[1];
    const float* V   = (const float*)d_in[2];
    const int*   pad = (const int*)d_in[3];
    float* out = (float*)d_out;
    int*   fz  = (int*)d_ws;

    fz_kernel<<<dim3(2), dim3(256), 0, stream>>>(pad, fz);
    attn_fwd<<<dim3(S_LEN / QT, NBH), dim3(256), 0, stream>>>(Q, K, V, pad, out);
    fixup_kernel<<<dim3(NBH), dim3(256), 0, stream>>>(V, fz, out);
}

// Round 3
// 107.536 us; speedup vs baseline: 2.6772x; 2.0988x over previous
//
#include <hip/hip_runtime.h>
#include <hip/hip_bf16.h>

#define S_LEN 2048
#define DH    64
#define NBH   32          // B*H
#define QT    128         // q rows per block (4 warps x 32)
#define KVT   64

typedef __attribute__((ext_vector_type(8)))  short short8;
typedef __attribute__((ext_vector_type(4)))  float f32x4;
typedef __attribute__((ext_vector_type(16))) float f32x16;

static __device__ __forceinline__ unsigned cvtpk_bf16(float a, float b) {
    unsigned r;
    asm("v_cvt_pk_bf16_f32 %0, %1, %2" : "=v"(r) : "v"(a), "v"(b));
    return r;
}

// ---------------------------------------------------------------------------
// Flash attention, swapped-operand 32x32x16 MFMA structure.
// grid = (S/QT, B*H), block = 256 (4 waves, 32 q-rows per wave)
// K LDS:  [key][d]  bf16, rows 128B, chunk ^= row&7 swizzle
// V LDS:  [d][key]  bf16 (transposed), same swizzle
// ---------------------------------------------------------------------------
__global__ __launch_bounds__(256)
void attn_fwd(const float* __restrict__ Q, const float* __restrict__ K,
              const float* __restrict__ V, const int* __restrict__ pad,
              float* __restrict__ out)
{
    __shared__ __align__(16) char  ldsK[2][KVT * 128];
    __shared__ __align__(16) char  ldsV[2][DH * 128];
    __shared__ __align__(16) float ldsPB[2][KVT];

    const int tid  = threadIdx.x;
    const int lane = tid & 63;
    const int wid  = tid >> 6;
    const int bx   = gridDim.x - 1 - blockIdx.x;   // heavy (diagonal-long) blocks first
    const int bh   = blockIdx.y;
    const int b    = bh >> 4;

    const int q0   = bx * QT;
    const int q0w  = q0 + wid * 32;
    const long base = (long)bh * S_LEN * DH;

    const int lq = lane & 31;      // this lane's q-row (col of C) / key row (A)
    const int hi = lane >> 5;

    // ---- Q fragments (B operand), scale = (1/8)*log2(e) folded ----
    const float QS = 0.18033688011112042f;
    short8 bq[4];
    {
        const float* qp = Q + base + (long)(q0w + lq) * DH;
        #pragma unroll
        for (int s = 0; s < 4; ++s) {
            int d0 = s * 16 + hi * 8;
            f32x4 x = *(const f32x4*)(qp + d0);
            f32x4 y = *(const f32x4*)(qp + d0 + 4);
            union { short8 s8; unsigned u[4]; } u;
            u.u[0] = cvtpk_bf16(x[0] * QS, x[1] * QS);
            u.u[1] = cvtpk_bf16(x[2] * QS, x[3] * QS);
            u.u[2] = cvtpk_bf16(y[0] * QS, y[1] * QS);
            u.u[3] = cvtpk_bf16(y[2] * QS, y[3] * QS);
            bq[s] = u.s8;
        }
    }

    f32x16 o0, o1;
    #pragma unroll
    for (int r = 0; r < 16; ++r) { o0[r] = 0.f; o1[r] = 0.f; }
    float m_run = -1e30f, l_run = 0.f;

    const int nkv = 2 * (bx + 1);

    // staging registers (issued early, written to LDS late -> T14)
    f32x4 kst[4], vst[4];
    int   pst = 0;
    const int vdg = tid & 15, vkq = tid >> 4;
    const float* Kb = K + base;
    const float* Vb = V + base;

    auto stage_load = [&](int t) {
        const float* kp = Kb + t * (KVT * DH);
        #pragma unroll
        for (int i = 0; i < 4; ++i)
            kst[i] = *(const f32x4*)(kp + i * 1024 + tid * 4);
        const float* vp = Vb + t * (KVT * DH);
        #pragma unroll
        for (int j = 0; j < 4; ++j)
            vst[j] = *(const f32x4*)(vp + (vkq * 4 + j) * DH + vdg * 4);
        pst = pad[b * S_LEN + t * KVT + (tid & 63)];
    };
    auto stage_write = [&](int buf) {
        char* kB = ldsK[buf];
        #pragma unroll
        for (int i = 0; i < 4; ++i) {
            int f = i * 1024 + tid * 4;
            int row = f >> 6, dc = f & 63;
            unsigned lo = cvtpk_bf16(kst[i][0], kst[i][1]);
            unsigned h2 = cvtpk_bf16(kst[i][2], kst[i][3]);
            int ch = (dc >> 3) ^ (row & 7);
            *(uint2*)(kB + row * 128 + ch * 16 + (dc & 7) * 2) = make_uint2(lo, h2);
        }
        char* vB = ldsV[buf];
        #pragma unroll
        for (int i = 0; i < 4; ++i) {
            int d = vdg * 4 + i;
            unsigned lo = cvtpk_bf16(vst[0][i], vst[1][i]);
            unsigned h2 = cvtpk_bf16(vst[2][i], vst[3][i]);
            int ch = (vkq >> 1) ^ (d & 7);
            *(uint2*)(vB + d * 128 + ch * 16 + (vkq & 1) * 8) = make_uint2(lo, h2);
        }
        if (tid < KVT) ldsPB[buf][tid] = pst ? -1e30f : 0.f;
    };

    // prologue: stage tile 0
    stage_load(0);
    stage_write(0);
    __syncthreads();

    for (int t = 0; t < nkv; ++t) {
        const int cur = t & 1;
        const int kv0 = t * KVT;
        if (t + 1 < nkv) stage_load(t + 1);   // issue HBM loads early

        if (kv0 <= q0w + 31) {                // tile has unmasked keys for this warp
            const char*  kB = ldsK[cur];
            const char*  vB = ldsV[cur];
            const float* pb = ldsPB[cur];
            const int    rsw = lq & 7;

            // ---- acc init = pad bias (broadcast f32x4 reads) ----
            f32x16 s0, s1;
            #pragma unroll
            for (int g = 0; g < 4; ++g) {
                f32x4 p0 = *(const f32x4*)(pb + g * 8 + hi * 4);
                f32x4 p1 = *(const f32x4*)(pb + 32 + g * 8 + hi * 4);
                #pragma unroll
                for (int i = 0; i < 4; ++i) { s0[g * 4 + i] = p0[i]; s1[g * 4 + i] = p1[i]; }
            }

            // ---- S^T = K Q^T : rows=keys, cols=q ----
            __builtin_amdgcn_s_setprio(1);
            #pragma unroll
            for (int s = 0; s < 4; ++s) {
                int ch = (((s * 2 + hi) ^ rsw) * 16);
                short8 ak0 = *(const short8*)(kB + lq * 128 + ch);
                short8 ak1 = *(const short8*)(kB + (32 + lq) * 128 + ch);
                s0 = __builtin_amdgcn_mfma_f32_32x32x16_bf16(ak0, bq[s], s0, 0, 0, 0);
                s1 = __builtin_amdgcn_mfma_f32_32x32x16_bf16(ak1, bq[s], s1, 0, 0, 0);
            }
            __builtin_amdgcn_s_setprio(0);

            // ---- causal mask (diagonal tiles only) ----
            if (kv0 + 63 > q0w) {
                int q = q0w + lq;
                #pragma unroll
                for (int r = 0; r < 16; ++r) {
                    int key0 = kv0 + (r & 3) + 8 * (r >> 2) + 4 * hi;
                    if (key0 > q)      s0[r] = -1e30f;
                    if (key0 + 32 > q) s1[r] = -1e30f;
                }
            }

            // ---- online softmax, lane-local rows, T13 defer-max ----
            float bm = -1e30f;
            #pragma unroll
            for (int r = 0; r < 16; ++r) bm = fmaxf(bm, fmaxf(s0[r], s1[r]));
            bm = fmaxf(bm, __shfl_xor(bm, 32));
            if (__any(bm > m_run + 8.0f)) {
                float mnew = fmaxf(m_run, bm);
                float c = exp2f(m_run - mnew);
                m_run = mnew;
                l_run *= c;
                #pragma unroll
                for (int r = 0; r < 16; ++r) { o0[r] *= c; o1[r] *= c; }
            }
            float rs = 0.f;
            #pragma unroll
            for (int r = 0; r < 16; ++r) {
                float p0 = exp2f(s0[r] - m_run);
                float p1 = exp2f(s1[r] - m_run);
                s0[r] = p0; s1[r] = p1;
                rs += p0 + p1;
            }
            rs += __shfl_xor(rs, 32);
            l_run += rs;

            // ---- refragment P -> bf16 B-operand (cvt_pk + permlane32_swap) ----
            short8 pfr[4];
            #pragma unroll
            for (int fs = 0; fs < 4; ++fs) {
                const f32x16& sp = (fs < 2) ? s0 : s1;
                const int rb = (fs & 1) * 8;
                unsigned a0 = cvtpk_bf16(sp[rb + 0], sp[rb + 1]);
                unsigned b0 = cvtpk_bf16(sp[rb + 4], sp[rb + 5]);
                asm("v_permlane32_swap_b32 %0, %1" : "+v"(a0), "+v"(b0));
                unsigned a1 = cvtpk_bf16(sp[rb + 2], sp[rb + 3]);
                unsigned b1 = cvtpk_bf16(sp[rb + 6], sp[rb + 7]);
                asm("v_permlane32_swap_b32 %0, %1" : "+v"(a1), "+v"(b1));
                union { short8 s8; unsigned u[4]; } u;
                u.u[0] = a0; u.u[1] = a1; u.u[2] = b0; u.u[3] = b1;
                pfr[fs] = u.s8;
            }

            // ---- O^T += V^T P^T : rows=d, cols=q ----
            __builtin_amdgcn_s_setprio(1);
            #pragma unroll
            for (int fs = 0; fs < 4; ++fs) {
                int ch = (((fs * 2 + hi) ^ rsw) * 16);
                short8 av0 = *(const short8*)(vB + lq * 128 + ch);
                short8 av1 = *(const short8*)(vB + (32 + lq) * 128 + ch);
                o0 = __builtin_amdgcn_mfma_f32_32x32x16_bf16(av0, pfr[fs], o0, 0, 0, 0);
                o1 = __builtin_amdgcn_mfma_f32_32x32x16_bf16(av1, pfr[fs], o1, 0, 0, 0);
            }
            __builtin_amdgcn_s_setprio(0);
        }

        if (t + 1 < nkv) stage_write((t + 1) & 1);   // vmcnt drain + LDS write, late
        __syncthreads();
    }

    // ---- epilogue: out[q][d], q = lane-local ----
    float invl = 1.0f / l_run;
    float* op = out + base + (long)(q0w + lq) * DH;
    #pragma unroll
    for (int g = 0; g < 4; ++g) {
        f32x4 w0, w1;
        #pragma unroll
        for (int i = 0; i < 4; ++i) {
            w0[i] = o0[g * 4 + i] * invl;
            w1[i] = o1[g * 4 + i] * invl;
        }
        *(f32x4*)(op + g * 8 + hi * 4)      = w0;
        *(f32x4*)(op + 32 + g * 8 + hi * 4) = w1;
    }
}

// ---------------------------------------------------------------------------
// first_zero[b] = min k with pad[b,k]==0 (S if none)
// ---------------------------------------------------------------------------
__global__ void fz_kernel(const int* __restrict__ pad, int* __restrict__ fz)
{
    int b = blockIdx.x;
    __shared__ int red[256];
    int local = S_LEN;
    for (int k = threadIdx.x; k < S_LEN; k += 256)
        if (pad[b * S_LEN + k] == 0 && k < local) local = k;
    red[threadIdx.x] = local;
    __syncthreads();
    for (int s = 128; s > 0; s >>= 1) {
        if (threadIdx.x < s) red[threadIdx.x] = min(red[threadIdx.x], red[threadIdx.x + s]);
        __syncthreads();
    }
    if (threadIdx.x == 0) fz[b] = red[0];
}

// ---------------------------------------------------------------------------
// meanv[bh][d] = mean over all 2048 keys of V[bh,:,d]  (only if fz[b] > 0).
// 1024 threads: t&15 = d-float4 chunk, t>>4 = key partition (64 partials).
// ---------------------------------------------------------------------------
__global__ __launch_bounds__(1024)
void meanv_kernel(const float* __restrict__ V, const int* __restrict__ fz,
                  float* __restrict__ meanv)
{
    const int bh = blockIdx.x;
    const int b  = bh >> 4;
    if (fz[b] <= 0) return;

    const int d4 = threadIdx.x & 15;
    const int kp = threadIdx.x >> 4;          // 0..63
    const float* vp = V + (long)bh * S_LEN * DH;

    f32x4 acc = (f32x4){0.f, 0.f, 0.f, 0.f};
    #pragma unroll 4
    for (int k = kp; k < S_LEN; k += 64)
        acc += *(const f32x4*)(vp + (long)k * DH + d4 * 4);

    __shared__ f32x4 red[64][16];
    red[kp][d4] = acc;
    __syncthreads();
    #pragma unroll
    for (int s = 32; s >= 1; s >>= 1) {
        if (kp < s) red[kp][d4] += red[kp + s][d4];
        __syncthreads();
    }
    if (kp == 0) {
        f32x4 m = red[0][d4] * (1.0f / 2048.0f);
        *(f32x4*)(meanv + bh * DH + d4 * 4) = m;
    }
}

// ---------------------------------------------------------------------------
// Rows q < first_zero[b]: reference softmax degenerates to uniform over ALL
// keys (scores all exactly -1e9 in fp32) -> out = mean(V). Overwrite them.
// ---------------------------------------------------------------------------
__global__ void fixup_kernel(const int* __restrict__ fz, const float* __restrict__ meanv,
                             float* __restrict__ out)
{
    const int bh = blockIdx.x;
    const int b  = bh >> 4;
    const int n  = fz[b];
    if (n <= 0) return;

    __shared__ float mv[DH];
    if (threadIdx.x < DH) mv[threadIdx.x] = meanv[bh * DH + threadIdx.x];
    __syncthreads();

    float* op = out + (long)bh * S_LEN * DH;
    for (int i = threadIdx.x; i < n * DH; i += 256) op[i] = mv[i & 63];
}

extern "C" void kernel_launch(void* const* d_in, const int* in_sizes, int n_in,
                              void* d_out, int out_size, void* d_ws, size_t ws_size,
                              hipStream_t stream)
{
    const float* Q   = (const float*)d_in[0];
    const float* K   = (const float*)d_in[1];
    const float* V   = (const float*)d_in[2];
    const int*   pad = (const int*)d_in[3];
    float* out   = (float*)d_out;
    int*   fz    = (int*)d_ws;
    float* meanv = (float*)((char*)d_ws + 256);

    fz_kernel<<<dim3(2), dim3(256), 0, stream>>>(pad, fz);
    attn_fwd<<<dim3(S_LEN / QT, NBH), dim3(256), 0, stream>>>(Q, K, V, pad, out);
    meanv_kernel<<<dim3(NBH), dim3(1024), 0, stream>>>(V, fz, meanv);
    fixup_kernel<<<dim3(NBH), dim3(256), 0, stream>>>(fz, meanv, out);
}

// Round 4
// 91.688 us; speedup vs baseline: 3.1399x; 1.1728x over previous
//
#include <hip/hip_runtime.h>
#include <hip/hip_bf16.h>

#define S_LEN 2048
#define DH    64
#define NBH   32          // B*H
#define QT    128         // q rows per block (4 warps x 32)
#define KVT   64
#define NTILE 32          // S/KVT

typedef __attribute__((ext_vector_type(8)))  short short8;
typedef __attribute__((ext_vector_type(4)))  float f32x4;
typedef __attribute__((ext_vector_type(16))) float f32x16;

static __device__ __forceinline__ unsigned cvtpk_bf16(float a, float b) {
    unsigned r;
    asm("v_cvt_pk_bf16_f32 %0, %1, %2" : "=v"(r) : "v"(a), "v"(b));
    return r;
}

typedef __attribute__((address_space(1))) const void gvoid_t;
typedef __attribute__((address_space(3))) void lvoid_t;
static __device__ __forceinline__ void gload16(const void* g, void* l) {
    __builtin_amdgcn_global_load_lds((gvoid_t*)g, (lvoid_t*)l, 16, 0, 0);
}
static __device__ __forceinline__ void gload4(const void* g, void* l) {
    __builtin_amdgcn_global_load_lds((gvoid_t*)g, (lvoid_t*)l, 4, 0, 0);
}

// ---------------------------------------------------------------------------
// Pre-pass: K,V fp32 -> bf16 tile images, byte-identical to the attn LDS tiles.
// K image tile: [key 0..63][128B row], chunk ^= row&7 swizzle.
// V image tile: [d 0..63][128B row of keys], chunk=(kq>>1)^(d&7), transposed.
// grid = (NTILE, NBH), 256 threads.
// ---------------------------------------------------------------------------
__global__ __launch_bounds__(256)
void prep_kernel(const float* __restrict__ K, const float* __restrict__ V,
                 char* __restrict__ Kimg, char* __restrict__ Vimg)
{
    const int t   = blockIdx.x;
    const int bh  = blockIdx.y;
    const int tid = threadIdx.x;
    const long tileOff = ((long)bh * NTILE + t) * 8192;
    const long srcOff  = (long)bh * S_LEN * DH + (long)t * KVT * DH;

    // K part
    {
        const float* kp = K + srcOff;
        char* dst = Kimg + tileOff;
        #pragma unroll
        for (int i = 0; i < 4; ++i) {
            int f = i * 1024 + tid * 4;
            int row = f >> 6, dc = f & 63;
            f32x4 x = *(const f32x4*)(kp + f);
            unsigned lo = cvtpk_bf16(x[0], x[1]);
            unsigned h2 = cvtpk_bf16(x[2], x[3]);
            int ch = (dc >> 3) ^ (row & 7);
            *(uint2*)(dst + row * 128 + ch * 16 + (dc & 7) * 2) = make_uint2(lo, h2);
        }
    }
    // V part (transpose)
    {
        const float* vp = V + srcOff;
        char* dst = Vimg + tileOff;
        const int vdg = tid & 15, vkq = tid >> 4;
        float rv[4][4];
        #pragma unroll
        for (int j = 0; j < 4; ++j) {
            f32x4 x = *(const f32x4*)(vp + (vkq * 4 + j) * DH + vdg * 4);
            rv[j][0] = x[0]; rv[j][1] = x[1]; rv[j][2] = x[2]; rv[j][3] = x[3];
        }
        #pragma unroll
        for (int i = 0; i < 4; ++i) {
            int d = vdg * 4 + i;
            unsigned lo = cvtpk_bf16(rv[0][i], rv[1][i]);
            unsigned h2 = cvtpk_bf16(rv[2][i], rv[3][i]);
            int ch = (vkq >> 1) ^ (d & 7);
            *(uint2*)(dst + d * 128 + ch * 16 + (vkq & 1) * 8) = make_uint2(lo, h2);
        }
    }
}

// bias[b][k] = pad ? -1e30 : 0
__global__ __launch_bounds__(1024)
void bias_kernel(const int* __restrict__ pad, float* __restrict__ bias)
{
    int b = blockIdx.x;
    #pragma unroll
    for (int i = 0; i < 2; ++i) {
        int k = threadIdx.x + i * 1024;
        bias[b * S_LEN + k] = pad[b * S_LEN + k] ? -1e30f : 0.f;
    }
}

// ---------------------------------------------------------------------------
// Flash attention v2: global_load_lds staging from pre-swizzled images.
// 1-D grid of 512; mapping pairs blocks i and i+256 to complementary bx so
// each CU's two resident blocks sum to constant causal work.
// ---------------------------------------------------------------------------
__global__ __launch_bounds__(256)
void attn_fwd2(const float* __restrict__ Q, const char* __restrict__ Kimg,
               const char* __restrict__ Vimg, const float* __restrict__ bias,
               float* __restrict__ out)
{
    __shared__ __align__(16) char  ldsK[2][KVT * 128];
    __shared__ __align__(16) char  ldsV[2][DH * 128];
    __shared__ __align__(16) float ldsPB[2][KVT];

    const int tid  = threadIdx.x;
    const int lane = tid & 63;
    const int wid  = tid >> 6;

    const int gid  = blockIdx.x;
    const int half = gid >> 8;
    const int r    = gid & 255;
    const int bx   = half ? (r & 15) : 15 - (r & 15);
    const int bh   = (r >> 4) + (half << 4);
    const int b    = bh >> 4;

    const int q0w  = bx * QT + wid * 32;
    const long base = (long)bh * S_LEN * DH;

    const int lq = lane & 31;
    const int hi = lane >> 5;

    // ---- Q fragments (B operand), scale = (1/8)*log2(e) folded ----
    const float QS = 0.18033688011112042f;
    short8 bq[4];
    {
        const float* qp = Q + base + (long)(q0w + lq) * DH;
        #pragma unroll
        for (int s = 0; s < 4; ++s) {
            int d0 = s * 16 + hi * 8;
            f32x4 x = *(const f32x4*)(qp + d0);
            f32x4 y = *(const f32x4*)(qp + d0 + 4);
            union { short8 s8; unsigned u[4]; } u;
            u.u[0] = cvtpk_bf16(x[0] * QS, x[1] * QS);
            u.u[1] = cvtpk_bf16(x[2] * QS, x[3] * QS);
            u.u[2] = cvtpk_bf16(y[0] * QS, y[1] * QS);
            u.u[3] = cvtpk_bf16(y[2] * QS, y[3] * QS);
            bq[s] = u.s8;
        }
    }

    f32x16 o0, o1;
    #pragma unroll
    for (int rr = 0; rr < 16; ++rr) { o0[rr] = 0.f; o1[rr] = 0.f; }
    float m_run = -1e30f, l_run = 0.f;

    const int nkv = 2 * (bx + 1);
    const char*  KimgB = Kimg + (long)bh * NTILE * 8192;
    const char*  VimgB = Vimg + (long)bh * NTILE * 8192;
    const float* biasB = bias + b * S_LEN;

    // stage tile t into buf: pure global_load_lds (16B), 4 segs/warp + bias
    auto stage = [&](int t, int buf) {
        if (wid < 2) {
            const char* src = KimgB + (long)t * 8192 + lane * 16;
            char* dst = ldsK[buf];
            #pragma unroll
            for (int s = 0; s < 4; ++s) {
                int seg = wid * 4 + s;
                gload16(src + seg * 1024, dst + seg * 1024);
            }
            if (wid == 0) gload4(biasB + t * KVT + lane, ldsPB[buf]);
        } else {
            const char* src = VimgB + (long)t * 8192 + lane * 16;
            char* dst = ldsV[buf];
            #pragma unroll
            for (int s = 0; s < 4; ++s) {
                int seg = (wid - 2) * 4 + s;
                gload16(src + seg * 1024, dst + seg * 1024);
            }
        }
    };

    // prologue
    stage(0, 0);
    asm volatile("s_waitcnt vmcnt(0)" ::: "memory");
    __syncthreads();

    for (int t = 0; t < nkv; ++t) {
        const int cur = t & 1;
        const int kv0 = t * KVT;
        if (t + 1 < nkv) stage(t + 1, cur ^ 1);   // issue next-tile loads early

        if (kv0 <= q0w + 31) {
            const char*  kB = ldsK[cur];
            const char*  vB = ldsV[cur];
            const float* pb = ldsPB[cur];
            const int    rsw = lq & 7;

            // ---- acc init = pad bias (broadcast f32x4 reads) ----
            f32x16 s0, s1;
            #pragma unroll
            for (int g = 0; g < 4; ++g) {
                f32x4 p0 = *(const f32x4*)(pb + g * 8 + hi * 4);
                f32x4 p1 = *(const f32x4*)(pb + 32 + g * 8 + hi * 4);
                #pragma unroll
                for (int i = 0; i < 4; ++i) { s0[g * 4 + i] = p0[i]; s1[g * 4 + i] = p1[i]; }
            }

            // ---- S^T = K Q^T ----
            __builtin_amdgcn_s_setprio(1);
            #pragma unroll
            for (int s = 0; s < 4; ++s) {
                int ch = (((s * 2 + hi) ^ rsw) * 16);
                short8 ak0 = *(const short8*)(kB + lq * 128 + ch);
                short8 ak1 = *(const short8*)(kB + (32 + lq) * 128 + ch);
                s0 = __builtin_amdgcn_mfma_f32_32x32x16_bf16(ak0, bq[s], s0, 0, 0, 0);
                s1 = __builtin_amdgcn_mfma_f32_32x32x16_bf16(ak1, bq[s], s1, 0, 0, 0);
            }
            __builtin_amdgcn_s_setprio(0);

            // ---- causal mask (diagonal tiles only) ----
            if (kv0 + 63 > q0w) {
                int q = q0w + lq;
                #pragma unroll
                for (int rr = 0; rr < 16; ++rr) {
                    int key0 = kv0 + (rr & 3) + 8 * (rr >> 2) + 4 * hi;
                    if (key0 > q)      s0[rr] = -1e30f;
                    if (key0 + 32 > q) s1[rr] = -1e30f;
                }
            }

            // ---- online softmax, lane-local rows, T13 defer-max ----
            float bm = -1e30f;
            #pragma unroll
            for (int rr = 0; rr < 16; ++rr) bm = fmaxf(bm, fmaxf(s0[rr], s1[rr]));
            bm = fmaxf(bm, __shfl_xor(bm, 32));
            if (__any(bm > m_run + 8.0f)) {
                float mnew = fmaxf(m_run, bm);
                float c = exp2f(m_run - mnew);
                m_run = mnew;
                l_run *= c;
                #pragma unroll
                for (int rr = 0; rr < 16; ++rr) { o0[rr] *= c; o1[rr] *= c; }
            }
            float rs = 0.f;
            #pragma unroll
            for (int rr = 0; rr < 16; ++rr) {
                float p0 = exp2f(s0[rr] - m_run);
                float p1 = exp2f(s1[rr] - m_run);
                s0[rr] = p0; s1[rr] = p1;
                rs += p0 + p1;
            }
            rs += __shfl_xor(rs, 32);
            l_run += rs;

            // ---- refragment P -> bf16 (cvt_pk + permlane32_swap) ----
            short8 pfr[4];
            #pragma unroll
            for (int fs = 0; fs < 4; ++fs) {
                const f32x16& sp = (fs < 2) ? s0 : s1;
                const int rb = (fs & 1) * 8;
                unsigned a0 = cvtpk_bf16(sp[rb + 0], sp[rb + 1]);
                unsigned b0 = cvtpk_bf16(sp[rb + 4], sp[rb + 5]);
                asm("v_permlane32_swap_b32 %0, %1" : "+v"(a0), "+v"(b0));
                unsigned a1 = cvtpk_bf16(sp[rb + 2], sp[rb + 3]);
                unsigned b1 = cvtpk_bf16(sp[rb + 6], sp[rb + 7]);
                asm("v_permlane32_swap_b32 %0, %1" : "+v"(a1), "+v"(b1));
                union { short8 s8; unsigned u[4]; } u;
                u.u[0] = a0; u.u[1] = a1; u.u[2] = b0; u.u[3] = b1;
                pfr[fs] = u.s8;
            }

            // ---- O^T += V^T P^T ----
            __builtin_amdgcn_s_setprio(1);
            #pragma unroll
            for (int fs = 0; fs < 4; ++fs) {
                int ch = (((fs * 2 + hi) ^ rsw) * 16);
                short8 av0 = *(const short8*)(vB + lq * 128 + ch);
                short8 av1 = *(const short8*)(vB + (32 + lq) * 128 + ch);
                o0 = __builtin_amdgcn_mfma_f32_32x32x16_bf16(av0, pfr[fs], o0, 0, 0, 0);
                o1 = __builtin_amdgcn_mfma_f32_32x32x16_bf16(av1, pfr[fs], o1, 0, 0, 0);
            }
            __builtin_amdgcn_s_setprio(0);
        }

        asm volatile("s_waitcnt vmcnt(0)" ::: "memory");  // next-tile loads done
        __syncthreads();
    }

    // ---- epilogue ----
    float invl = 1.0f / l_run;
    float* op = out + base + (long)(q0w + lq) * DH;
    #pragma unroll
    for (int g = 0; g < 4; ++g) {
        f32x4 w0, w1;
        #pragma unroll
        for (int i = 0; i < 4; ++i) {
            w0[i] = o0[g * 4 + i] * invl;
            w1[i] = o1[g * 4 + i] * invl;
        }
        *(f32x4*)(op + g * 8 + hi * 4)      = w0;
        *(f32x4*)(op + 32 + g * 8 + hi * 4) = w1;
    }
}

// ---------------------------------------------------------------------------
// Legacy path (round-3 kernel), used only if ws_size is too small for images.
// ---------------------------------------------------------------------------
__global__ __launch_bounds__(256)
void attn_fwd(const float* __restrict__ Q, const float* __restrict__ K,
              const float* __restrict__ V, const int* __restrict__ pad,
              float* __restrict__ out)
{
    __shared__ __align__(16) char  ldsK[2][KVT * 128];
    __shared__ __align__(16) char  ldsV[2][DH * 128];
    __shared__ __align__(16) float ldsPB[2][KVT];

    const int tid  = threadIdx.x;
    const int lane = tid & 63;
    const int wid  = tid >> 6;
    const int bx   = gridDim.x - 1 - blockIdx.x;
    const int bh   = blockIdx.y;
    const int b    = bh >> 4;

    const int q0w  = bx * QT + wid * 32;
    const long base = (long)bh * S_LEN * DH;
    const int lq = lane & 31;
    const int hi = lane >> 5;

    const float QS = 0.18033688011112042f;
    short8 bq[4];
    {
        const float* qp = Q + base + (long)(q0w + lq) * DH;
        #pragma unroll
        for (int s = 0; s < 4; ++s) {
            int d0 = s * 16 + hi * 8;
            f32x4 x = *(const f32x4*)(qp + d0);
            f32x4 y = *(const f32x4*)(qp + d0 + 4);
            union { short8 s8; unsigned u[4]; } u;
            u.u[0] = cvtpk_bf16(x[0] * QS, x[1] * QS);
            u.u[1] = cvtpk_bf16(x[2] * QS, x[3] * QS);
            u.u[2] = cvtpk_bf16(y[0] * QS, y[1] * QS);
            u.u[3] = cvtpk_bf16(y[2] * QS, y[3] * QS);
            bq[s] = u.s8;
        }
    }

    f32x16 o0, o1;
    #pragma unroll
    for (int rr = 0; rr < 16; ++rr) { o0[rr] = 0.f; o1[rr] = 0.f; }
    float m_run = -1e30f, l_run = 0.f;

    const int nkv = 2 * (bx + 1);
    f32x4 kst[4], vst[4];
    int   pst = 0;
    const int vdg = tid & 15, vkq = tid >> 4;
    const float* Kb = K + base;
    const float* Vb = V + base;

    auto stage_load = [&](int t) {
        const float* kp = Kb + t * (KVT * DH);
        #pragma unroll
        for (int i = 0; i < 4; ++i) kst[i] = *(const f32x4*)(kp + i * 1024 + tid * 4);
        const float* vp = Vb + t * (KVT * DH);
        #pragma unroll
        for (int j = 0; j < 4; ++j) vst[j] = *(const f32x4*)(vp + (vkq * 4 + j) * DH + vdg * 4);
        pst = pad[b * S_LEN + t * KVT + (tid & 63)];
    };
    auto stage_write = [&](int buf) {
        char* kB = ldsK[buf];
        #pragma unroll
        for (int i = 0; i < 4; ++i) {
            int f = i * 1024 + tid * 4;
            int row = f >> 6, dc = f & 63;
            unsigned lo = cvtpk_bf16(kst[i][0], kst[i][1]);
            unsigned h2 = cvtpk_bf16(kst[i][2], kst[i][3]);
            int ch = (dc >> 3) ^ (row & 7);
            *(uint2*)(kB + row * 128 + ch * 16 + (dc & 7) * 2) = make_uint2(lo, h2);
        }
        char* vB = ldsV[buf];
        #pragma unroll
        for (int i = 0; i < 4; ++i) {
            int d = vdg * 4 + i;
            unsigned lo = cvtpk_bf16(vst[0][i], vst[1][i]);
            unsigned h2 = cvtpk_bf16(vst[2][i], vst[3][i]);
            int ch = (vkq >> 1) ^ (d & 7);
            *(uint2*)(vB + d * 128 + ch * 16 + (vkq & 1) * 8) = make_uint2(lo, h2);
        }
        if (tid < KVT) ldsPB[buf][tid] = pst ? -1e30f : 0.f;
    };

    stage_load(0);
    stage_write(0);
    __syncthreads();

    for (int t = 0; t < nkv; ++t) {
        const int cur = t & 1;
        const int kv0 = t * KVT;
        if (t + 1 < nkv) stage_load(t + 1);

        if (kv0 <= q0w + 31) {
            const char*  kB = ldsK[cur];
            const char*  vB = ldsV[cur];
            const float* pb = ldsPB[cur];
            const int    rsw = lq & 7;
            f32x16 s0, s1;
            #pragma unroll
            for (int g = 0; g < 4; ++g) {
                f32x4 p0 = *(const f32x4*)(pb + g * 8 + hi * 4);
                f32x4 p1 = *(const f32x4*)(pb + 32 + g * 8 + hi * 4);
                #pragma unroll
                for (int i = 0; i < 4; ++i) { s0[g * 4 + i] = p0[i]; s1[g * 4 + i] = p1[i]; }
            }
            __builtin_amdgcn_s_setprio(1);
            #pragma unroll
            for (int s = 0; s < 4; ++s) {
                int ch = (((s * 2 + hi) ^ rsw) * 16);
                short8 ak0 = *(const short8*)(kB + lq * 128 + ch);
                short8 ak1 = *(const short8*)(kB + (32 + lq) * 128 + ch);
                s0 = __builtin_amdgcn_mfma_f32_32x32x16_bf16(ak0, bq[s], s0, 0, 0, 0);
                s1 = __builtin_amdgcn_mfma_f32_32x32x16_bf16(ak1, bq[s], s1, 0, 0, 0);
            }
            __builtin_amdgcn_s_setprio(0);
            if (kv0 + 63 > q0w) {
                int q = q0w + lq;
                #pragma unroll
                for (int rr = 0; rr < 16; ++rr) {
                    int key0 = kv0 + (rr & 3) + 8 * (rr >> 2) + 4 * hi;
                    if (key0 > q)      s0[rr] = -1e30f;
                    if (key0 + 32 > q) s1[rr] = -1e30f;
                }
            }
            float bm = -1e30f;
            #pragma unroll
            for (int rr = 0; rr < 16; ++rr) bm = fmaxf(bm, fmaxf(s0[rr], s1[rr]));
            bm = fmaxf(bm, __shfl_xor(bm, 32));
            if (__any(bm > m_run + 8.0f)) {
                float mnew = fmaxf(m_run, bm);
                float c = exp2f(m_run - mnew);
                m_run = mnew; l_run *= c;
                #pragma unroll
                for (int rr = 0; rr < 16; ++rr) { o0[rr] *= c; o1[rr] *= c; }
            }
            float rs = 0.f;
            #pragma unroll
            for (int rr = 0; rr < 16; ++rr) {
                float p0 = exp2f(s0[rr] - m_run);
                float p1 = exp2f(s1[rr] - m_run);
                s0[rr] = p0; s1[rr] = p1;
                rs += p0 + p1;
            }
            rs += __shfl_xor(rs, 32);
            l_run += rs;
            short8 pfr[4];
            #pragma unroll
            for (int fs = 0; fs < 4; ++fs) {
                const f32x16& sp = (fs < 2) ? s0 : s1;
                const int rb = (fs & 1) * 8;
                unsigned a0 = cvtpk_bf16(sp[rb + 0], sp[rb + 1]);
                unsigned b0 = cvtpk_bf16(sp[rb + 4], sp[rb + 5]);
                asm("v_permlane32_swap_b32 %0, %1" : "+v"(a0), "+v"(b0));
                unsigned a1 = cvtpk_bf16(sp[rb + 2], sp[rb + 3]);
                unsigned b1 = cvtpk_bf16(sp[rb + 6], sp[rb + 7]);
                asm("v_permlane32_swap_b32 %0, %1" : "+v"(a1), "+v"(b1));
                union { short8 s8; unsigned u[4]; } u;
                u.u[0] = a0; u.u[1] = a1; u.u[2] = b0; u.u[3] = b1;
                pfr[fs] = u.s8;
            }
            __builtin_amdgcn_s_setprio(1);
            #pragma unroll
            for (int fs = 0; fs < 4; ++fs) {
                int ch = (((fs * 2 + hi) ^ rsw) * 16);
                short8 av0 = *(const short8*)(vB + lq * 128 + ch);
                short8 av1 = *(const short8*)(vB + (32 + lq) * 128 + ch);
                o0 = __builtin_amdgcn_mfma_f32_32x32x16_bf16(av0, pfr[fs], o0, 0, 0, 0);
                o1 = __builtin_amdgcn_mfma_f32_32x32x16_bf16(av1, pfr[fs], o1, 0, 0, 0);
            }
            __builtin_amdgcn_s_setprio(0);
        }
        if (t + 1 < nkv) stage_write((t + 1) & 1);
        __syncthreads();
    }

    float invl = 1.0f / l_run;
    float* op = out + base + (long)(q0w + lq) * DH;
    #pragma unroll
    for (int g = 0; g < 4; ++g) {
        f32x4 w0, w1;
        #pragma unroll
        for (int i = 0; i < 4; ++i) {
            w0[i] = o0[g * 4 + i] * invl;
            w1[i] = o1[g * 4 + i] * invl;
        }
        *(f32x4*)(op + g * 8 + hi * 4)      = w0;
        *(f32x4*)(op + 32 + g * 8 + hi * 4) = w1;
    }
}

// ---------------------------------------------------------------------------
__global__ void fz_kernel(const int* __restrict__ pad, int* __restrict__ fz)
{
    int b = blockIdx.x;
    __shared__ int red[256];
    int local = S_LEN;
    for (int k = threadIdx.x; k < S_LEN; k += 256)
        if (pad[b * S_LEN + k] == 0 && k < local) local = k;
    red[threadIdx.x] = local;
    __syncthreads();
    for (int s = 128; s > 0; s >>= 1) {
        if (threadIdx.x < s) red[threadIdx.x] = min(red[threadIdx.x], red[threadIdx.x + s]);
        __syncthreads();
    }
    if (threadIdx.x == 0) fz[b] = red[0];
}

__global__ __launch_bounds__(1024)
void meanv_kernel(const float* __restrict__ V, const int* __restrict__ fz,
                  float* __restrict__ meanv)
{
    const int bh = blockIdx.x;
    const int b  = bh >> 4;
    if (fz[b] <= 0) return;
    const int d4 = threadIdx.x & 15;
    const int kp = threadIdx.x >> 4;
    const float* vp = V + (long)bh * S_LEN * DH;
    f32x4 acc = (f32x4){0.f, 0.f, 0.f, 0.f};
    #pragma unroll 4
    for (int k = kp; k < S_LEN; k += 64)
        acc += *(const f32x4*)(vp + (long)k * DH + d4 * 4);
    __shared__ f32x4 red[64][16];
    red[kp][d4] = acc;
    __syncthreads();
    #pragma unroll
    for (int s = 32; s >= 1; s >>= 1) {
        if (kp < s) red[kp][d4] += red[kp + s][d4];
        __syncthreads();
    }
    if (kp == 0)
        *(f32x4*)(meanv + bh * DH + d4 * 4) = red[0][d4] * (1.0f / 2048.0f);
}

__global__ void fixup_kernel(const int* __restrict__ fz, const float* __restrict__ meanv,
                             float* __restrict__ out)
{
    const int bh = blockIdx.x;
    const int b  = bh >> 4;
    const int n  = fz[b];
    if (n <= 0) return;
    __shared__ float mv[DH];
    if (threadIdx.x < DH) mv[threadIdx.x] = meanv[bh * DH + threadIdx.x];
    __syncthreads();
    float* op = out + (long)bh * S_LEN * DH;
    for (int i = threadIdx.x; i < n * DH; i += 256) op[i] = mv[i & 63];
}

extern "C" void kernel_launch(void* const* d_in, const int* in_sizes, int n_in,
                              void* d_out, int out_size, void* d_ws, size_t ws_size,
                              hipStream_t stream)
{
    const float* Q   = (const float*)d_in[0];
    const float* K   = (const float*)d_in[1];
    const float* V   = (const float*)d_in[2];
    const int*   pad = (const int*)d_in[3];
    float* out   = (float*)d_out;

    int*   fz    = (int*)d_ws;
    float* meanv = (float*)((char*)d_ws + 256);
    float* bias  = (float*)((char*)d_ws + 8448);
    char*  Kimg  = (char*)d_ws + 32768;
    char*  Vimg  = Kimg + (size_t)NBH * NTILE * 8192;
    const size_t need = 32768 + 2 * (size_t)NBH * NTILE * 8192;   // ~16.8 MB

    fz_kernel<<<dim3(2), dim3(256), 0, stream>>>(pad, fz);
    if (ws_size >= need) {
        bias_kernel<<<dim3(2), dim3(1024), 0, stream>>>(pad, bias);
        prep_kernel<<<dim3(NTILE, NBH), dim3(256), 0, stream>>>(K, V, Kimg, Vimg);
        attn_fwd2<<<dim3(512), dim3(256), 0, stream>>>(Q, Kimg, Vimg, bias, out);
    } else {
        attn_fwd<<<dim3(S_LEN / QT, NBH), dim3(256), 0, stream>>>(Q, K, V, pad, out);
    }
    meanv_kernel<<<dim3(NBH), dim3(1024), 0, stream>>>(V, fz, meanv);
    fixup_kernel<<<dim3(NBH), dim3(256), 0, stream>>>(fz, meanv, out);
}